// Round 15
// baseline (120.245 us; speedup 1.0000x reference)
//
#include <hip/hip_runtime.h>
#include <math.h>

#define Bn 8
#define Cn 512
#define Kn 64
#define C4n 128
#define Nn 4096

typedef short bf16x8 __attribute__((ext_vector_type(8)));
typedef float f32x4  __attribute__((ext_vector_type(4)));
typedef unsigned short u16;

__device__ __forceinline__ u16 f2bf(float f) {
    union { float f; unsigned u; } v; v.f = f;
    unsigned r = v.u + 0x7FFF + ((v.u >> 16) & 1);   // RNE
    return (u16)(r >> 16);
}
__device__ __forceinline__ float bf2f(u16 h) {
    union { unsigned u; float f; } v; v.u = ((unsigned)h) << 16;
    return v.f;
}
__device__ __forceinline__ bf16x8 cvt8(const float* p) {
    float4 a = *(const float4*)p;
    float4 b = *(const float4*)(p + 4);
    bf16x8 r;
    r[0] = (short)f2bf(a.x); r[1] = (short)f2bf(a.y);
    r[2] = (short)f2bf(a.z); r[3] = (short)f2bf(a.w);
    r[4] = (short)f2bf(b.x); r[5] = (short)f2bf(b.y);
    r[6] = (short)f2bf(b.z); r[7] = (short)f2bf(b.w);
    return r;
}

// ---------------------------------------------------------------------------
// Single projection kernel, grid dim3(8, 8, 3), 256 threads.
//  z<2 : pv{z}h[b][c][k] = bf16(sum_c' y{z}[b,k,c']*wv[c,c'] + bv[c])
//  z==2: per-block LOCAL kk (y2·wk^T + bk -> LDS), then
//        Mth[b][k][c] = bf16(sum_d kk[k][d]*wq[d,c]) for its 64-c slice;
//        block x==0 also emits e0[b,k] = sum_d bq[d]*kk[k][d].
__global__ __launch_bounds__(256) void proj_kernel(
    const float* __restrict__ y1, const float* __restrict__ y2,
    const float* __restrict__ wv, const float* __restrict__ bv,
    const float* __restrict__ wk, const float* __restrict__ bk,
    const float* __restrict__ wq, const float* __restrict__ bq,
    u16* __restrict__ pv1h, u16* __restrict__ pv2h,
    u16* __restrict__ Mth, float* __restrict__ e0)
{
    __shared__ u16 kkL[64 * 136];   // [k][d] bf16, row-padded (+8) ~17.4 KB

    const int b    = blockIdx.y;
    const int sel  = blockIdx.z;
    const int lane = threadIdx.x & 63;
    const int wid  = threadIdx.x >> 6;
    const int lr   = lane & 15;
    const int lg   = lane >> 4;

    if (sel < 2) {
        // ---- pv ----
        const int cb   = blockIdx.x * 64 + wid * 16;
        const float* y = sel ? y2 : y1;
        u16* pvh       = sel ? pv2h : pv1h;

        f32x4 acc[4];
        #pragma unroll
        for (int kt = 0; kt < 4; ++kt) acc[kt] = (f32x4){0.f, 0.f, 0.f, 0.f};

        for (int c0 = 0; c0 < Cn; c0 += 32) {
            const int cf = c0 + lg * 8;
            bf16x8 wfr = cvt8(wv + (size_t)(cb + lr) * Cn + cf);
            bf16x8 yfr[4];
            #pragma unroll
            for (int kt = 0; kt < 4; ++kt)
                yfr[kt] = cvt8(y + (size_t)(b * Kn + kt * 16 + lr) * Cn + cf);
            #pragma unroll
            for (int kt = 0; kt < 4; ++kt)
                acc[kt] = __builtin_amdgcn_mfma_f32_16x16x32_bf16(
                    yfr[kt], wfr, acc[kt], 0, 0, 0);
        }
        const int c = cb + lr;
        const float bb = bv[c];
        #pragma unroll
        for (int kt = 0; kt < 4; ++kt) {
            ushort4 o;
            o.x = f2bf(acc[kt][0] + bb); o.y = f2bf(acc[kt][1] + bb);
            o.z = f2bf(acc[kt][2] + bb); o.w = f2bf(acc[kt][3] + bb);
            *(ushort4*)&pvh[(((size_t)(b * Cn + c)) << 6) + kt * 16 + 4 * lg] = o;
        }
        return;
    }

    // ---- z==2: local kk -> LDS, then M slice (+ e0 on block x==0) ----
    const int kt = wid;                 // wave's 16-k stripe: k = kt*16 + lr

    // y2 fragments for this k-stripe, held in registers (16 chunks of K=32)
    bf16x8 yfr[16];
    #pragma unroll
    for (int cc = 0; cc < 16; ++cc)
        yfr[cc] = cvt8(y2 + (size_t)(b * Kn + kt * 16 + lr) * Cn + cc * 32 + lg * 8);

    // kk[k][d] for all 128 d, 8 chunks of 16 d
    for (int dt = 0; dt < 8; ++dt) {
        f32x4 acc = (f32x4){0.f, 0.f, 0.f, 0.f};
        #pragma unroll
        for (int cc = 0; cc < 16; ++cc) {
            bf16x8 wfr = cvt8(wk + (size_t)(dt * 16 + lr) * Cn + cc * 32 + lg * 8);
            acc = __builtin_amdgcn_mfma_f32_16x16x32_bf16(wfr, yfr[cc], acc, 0, 0, 0);
        }
        // D: col(lane lr) = k = kt*16+lr, rows(reg) = d = dt*16 + 4*lg + reg
        const int d4 = dt * 16 + 4 * lg;
        float4 bkv = *(const float4*)&bk[d4];
        ushort4 o;
        o.x = f2bf(acc[0] + bkv.x); o.y = f2bf(acc[1] + bkv.y);
        o.z = f2bf(acc[2] + bkv.z); o.w = f2bf(acc[3] + bkv.w);
        *(ushort4*)&kkL[(kt * 16 + lr) * 136 + d4] = o;
    }
    __syncthreads();

    // e0 (block x==0 only): e0[b,k] = sum_d bq[d]*kk[k][d]
    if (blockIdx.x == 0 && threadIdx.x < Kn) {
        const int k = threadIdx.x;
        float acc = 0.f;
        #pragma unroll 16
        for (int d = 0; d < C4n; ++d)
            acc += bq[d] * bf2f(kkL[k * 136 + d]);
        e0[b * Kn + k] = acc;
    }

    // M slice: c in [blockIdx.x*64 + wid*16, +16)
    {
        const int cb = blockIdx.x * 64 + wid * 16;
        f32x4 acc[4];
        #pragma unroll
        for (int q = 0; q < 4; ++q) acc[q] = (f32x4){0.f, 0.f, 0.f, 0.f};

        for (int d0 = 0; d0 < C4n; d0 += 32) {
            const int df = d0 + lg * 8;
            // A-frag: wq^T[c][d] from strided scalar loads (wq is [d][c])
            bf16x8 afr;
            #pragma unroll
            for (int j = 0; j < 8; ++j)
                afr[j] = (short)f2bf(wq[(size_t)(df + j) * Cn + cb + lr]);
            #pragma unroll
            for (int q = 0; q < 4; ++q) {
                bf16x8 bfr = *(const bf16x8*)&kkL[(q * 16 + lr) * 136 + df];
                acc[q] = __builtin_amdgcn_mfma_f32_16x16x32_bf16(afr, bfr, acc[q], 0, 0, 0);
            }
        }
        // D: col(lane lr) = k = q*16 + lr (B col), rows(reg) = c = cb + 4*lg + reg (A row)
        #pragma unroll
        for (int q = 0; q < 4; ++q) {
            ushort4 o;
            o.x = f2bf(acc[q][0]); o.y = f2bf(acc[q][1]);
            o.z = f2bf(acc[q][2]); o.w = f2bf(acc[q][3]);
            *(ushort4*)&Mth[(size_t)(b * Kn + q * 16 + lr) * Cn + cb + 4 * lg] = o;
        }
    }
}

// ---------------------------------------------------------------------------
// Fused attention+output kernel (exact R9 structure — best wall config).
// Phase A: energy (operand-swapped MFMA, no staging) + softmax -> attL (LDS,
//          bf16, 16B-chunk XOR swizzle). One __syncthreads.
// Phase B: per-wave independent c-stripes; att frags in regs; per-wave LDS
//          relay T for line-coalesced float4 epilogue; NT stores. No barriers.
// Grid 512 (b = id&7 XCD-affine, 64-n tile = id>>3), 256 threads.
__global__ __launch_bounds__(256) void attn_out_kernel(
    const float* __restrict__ x1, const float* __restrict__ x2,
    const u16* __restrict__ pv1h, const u16* __restrict__ pv2h,
    const u16* __restrict__ Mth, const float* __restrict__ e0,
    const float* __restrict__ scale, const float* __restrict__ scale1,
    float* __restrict__ out1, float* __restrict__ out2)
{
    __shared__ u16   attL[64 * 64];       // swizzled [n][k]
    __shared__ float T[4][16 * 68];       // per-wave epilogue relay

    const int id   = blockIdx.x;
    const int b    = id & 7;
    const int n0   = (id >> 3) * 64;
    const int t    = threadIdx.x;
    const int lane = t & 63;
    const int wid  = t >> 6;
    const int lr   = lane & 15;
    const int lg   = lane >> 4;
    const int nl   = wid * 16 + lr;       // phase-A lane's local n

    // ---------------- Phase A: energy + softmax ----------------
    f32x4 eacc[4];
    #pragma unroll
    for (int kt = 0; kt < 4; ++kt) eacc[kt] = (f32x4){0.f, 0.f, 0.f, 0.f};

    const float* xcol = x2 + (((size_t)b * Cn) << 12) + n0 + nl;  // x2[b][c][n]
    const u16*   mb   = Mth + ((size_t)b << 15) + (size_t)lr * Cn;

    for (int c0 = 0; c0 < Cn; c0 += 32) {
        const int cf = c0 + lg * 8;
        float xs[8];
        #pragma unroll
        for (int j = 0; j < 8; ++j)
            xs[j] = xcol[((size_t)(cf + j)) << 12];
        bf16x8 xfr;
        #pragma unroll
        for (int j = 0; j < 8; ++j) xfr[j] = (short)f2bf(xs[j]);
        #pragma unroll
        for (int kt = 0; kt < 4; ++kt) {
            bf16x8 av = *(const bf16x8*)(mb + ((size_t)kt << 13) + cf);
            eacc[kt] = __builtin_amdgcn_mfma_f32_16x16x32_bf16(av, xfr, eacc[kt], 0, 0, 0);
        }
    }

    {
        float a[4][4];
        float mx = 0.f;   // |.| >= 0
        #pragma unroll
        for (int kt = 0; kt < 4; ++kt) {
            float4 e0v = *(const float4*)&e0[b * Kn + kt * 16 + lg * 4];
            float er[4] = {e0v.x, e0v.y, e0v.z, e0v.w};
            #pragma unroll
            for (int reg = 0; reg < 4; ++reg) {
                float v = fabsf(eacc[kt][reg] + er[reg]);
                a[kt][reg] = v;
                mx = fmaxf(mx, v);
            }
        }
        mx = fmaxf(mx, __shfl_xor(mx, 16));
        mx = fmaxf(mx, __shfl_xor(mx, 32));
        float s = 0.f;
        #pragma unroll
        for (int kt = 0; kt < 4; ++kt)
            #pragma unroll
            for (int reg = 0; reg < 4; ++reg) {
                a[kt][reg] = __expf(a[kt][reg] - mx);
                s += a[kt][reg];
            }
        s += __shfl_xor(s, 16);
        s += __shfl_xor(s, 32);
        const float inv = 1.0f / s;

        // store att row nl: k = kt*16 + 4*lg + {0..3}; 16B-chunk XOR swizzle
        #pragma unroll
        for (int kt = 0; kt < 4; ++kt) {
            ushort4 o;
            o.x = f2bf(a[kt][0] * inv); o.y = f2bf(a[kt][1] * inv);
            o.z = f2bf(a[kt][2] * inv); o.w = f2bf(a[kt][3] * inv);
            const int chunk = (kt * 2 + (lg >> 1)) ^ (nl & 7);
            *(ushort4*)&attL[nl * 64 + chunk * 8 + 4 * (lg & 1)] = o;
        }
    }
    __syncthreads();

    // att A-frags: A[row=n=nt*16+lr][k = ks*32 + lg*8 + j]
    bf16x8 af[4][2];
    #pragma unroll
    for (int nt = 0; nt < 4; ++nt)
        #pragma unroll
        for (int ks = 0; ks < 2; ++ks) {
            const int nn = nt * 16 + lr;
            const int chunk = (ks * 4 + lg) ^ (nn & 7);
            af[nt][ks] = *(const bf16x8*)&attL[nn * 64 + chunk * 8];
        }

    // ---------------- Phase B: 8 c-tiles, per-wave independent ----------------
    const float sA = scale[0], sB = scale1[0];
    float* Tw = &T[wid][0];

    for (int ct = 0; ct < 8; ++ct) {
        const int wc = ct * 64 + wid * 16;    // wave's 16-c stripe

        const u16* p1 = pv1h + (((size_t)(b * Cn + wc + lr)) << 6) + lg * 8;
        const u16* p2 = pv2h + (((size_t)(b * Cn + wc + lr)) << 6) + lg * 8;
        bf16x8 v1[2], v2[2];
        v1[0] = *(const bf16x8*)p1;  v1[1] = *(const bf16x8*)(p1 + 32);
        v2[0] = *(const bf16x8*)p2;  v2[1] = *(const bf16x8*)(p2 + 32);

        f32x4 acc1[4], acc2[4];
        #pragma unroll
        for (int nt = 0; nt < 4; ++nt) {
            f32x4 z = (f32x4){0.f, 0.f, 0.f, 0.f};
            acc1[nt] = __builtin_amdgcn_mfma_f32_16x16x32_bf16(af[nt][0], v1[0], z, 0, 0, 0);
            acc1[nt] = __builtin_amdgcn_mfma_f32_16x16x32_bf16(af[nt][1], v1[1], acc1[nt], 0, 0, 0);
            acc2[nt] = __builtin_amdgcn_mfma_f32_16x16x32_bf16(af[nt][0], v2[0], z, 0, 0, 0);
            acc2[nt] = __builtin_amdgcn_mfma_f32_16x16x32_bf16(af[nt][1], v2[1], acc2[nt], 0, 0, 0);
        }

        // ---- output 1: per-wave stage -> coalesced drain ----
        #pragma unroll
        for (int nt = 0; nt < 4; ++nt) {
            float4 v;
            v.x = acc1[nt][0]; v.y = acc1[nt][1];
            v.z = acc1[nt][2]; v.w = acc1[nt][3];
            *(float4*)&Tw[lr * 68 + nt * 16 + 4 * lg] = v;
        }
        #pragma unroll
        for (int r4 = 0; r4 < 4; ++r4) {
            const int rloc = r4 * 4 + lg;
            const size_t row = (((size_t)(b * Cn + wc + rloc)) << 12) + n0 + lr * 4;
            float4 a = *(const float4*)&Tw[rloc * 68 + lr * 4];
            float4 xv = *(const float4*)&x1[row];
            f32x4 o;
            o[0] = sA * a.x + xv.x;  o[1] = sA * a.y + xv.y;
            o[2] = sA * a.z + xv.z;  o[3] = sA * a.w + xv.w;
            __builtin_nontemporal_store(o, (f32x4*)&out1[row]);
        }

        // ---- output 2 ----
        #pragma unroll
        for (int nt = 0; nt < 4; ++nt) {
            float4 v;
            v.x = acc2[nt][0]; v.y = acc2[nt][1];
            v.z = acc2[nt][2]; v.w = acc2[nt][3];
            *(float4*)&Tw[lr * 68 + nt * 16 + 4 * lg] = v;
        }
        #pragma unroll
        for (int r4 = 0; r4 < 4; ++r4) {
            const int rloc = r4 * 4 + lg;
            const size_t row = (((size_t)(b * Cn + wc + rloc)) << 12) + n0 + lr * 4;
            float4 a = *(const float4*)&Tw[rloc * 68 + lr * 4];
            float4 xv = *(const float4*)&x2[row];
            f32x4 o;
            o[0] = sB * a.x + xv.x;  o[1] = sB * a.y + xv.y;
            o[2] = sB * a.z + xv.z;  o[3] = sB * a.w + xv.w;
            __builtin_nontemporal_store(o, (f32x4*)&out2[row]);
        }
    }
}

// ---------------------------------------------------------------------------
extern "C" void kernel_launch(void* const* d_in, const int* in_sizes, int n_in,
                              void* d_out, int out_size, void* d_ws, size_t ws_size,
                              hipStream_t stream)
{
    const float* x1     = (const float*)d_in[0];
    const float* y1     = (const float*)d_in[1];
    const float* x2     = (const float*)d_in[2];
    const float* y2     = (const float*)d_in[3];
    const float* wq     = (const float*)d_in[4];
    const float* bq     = (const float*)d_in[5];
    const float* wk     = (const float*)d_in[6];
    const float* bk     = (const float*)d_in[7];
    const float* wv     = (const float*)d_in[8];
    const float* bv     = (const float*)d_in[9];
    const float* scale  = (const float*)d_in[10];
    const float* scale1 = (const float*)d_in[11];

    float* out1 = (float*)d_out;
    float* out2 = out1 + (size_t)Bn * Cn * Nn;

    float* ws   = (float*)d_ws;
    float* e0   = ws;                       // 512 f
    u16*   Mth  = (u16*)(ws + 512);         // 262144 u16
    u16*   pv1h = Mth + 262144;             // 262144 u16
    u16*   pv2h = pv1h + 262144;            // 262144 u16

    proj_kernel<<<dim3(8, Bn, 3), 256, 0, stream>>>(
        y1, y2, wv, bv, wk, bk, wq, bq, pv1h, pv2h, Mth, e0);
    attn_out_kernel<<<512, 256, 0, stream>>>(
        x1, x2, pv1h, pv2h, Mth, e0, scale, scale1, out1, out2);
}

// Round 16
// 88.263 us; speedup vs baseline: 1.3624x; 1.3624x over previous
//
#include <hip/hip_runtime.h>
#include <math.h>

#define Bn 8
#define Cn 512
#define Kn 64
#define C4n 128
#define Nn 4096

typedef short bf16x8 __attribute__((ext_vector_type(8)));
typedef float f32x4  __attribute__((ext_vector_type(4)));
typedef unsigned short u16;

__device__ __forceinline__ u16 f2bf(float f) {
    union { float f; unsigned u; } v; v.f = f;
    unsigned r = v.u + 0x7FFF + ((v.u >> 16) & 1);   // RNE
    return (u16)(r >> 16);
}
__device__ __forceinline__ float bf2f(u16 h) {
    union { unsigned u; float f; } v; v.u = ((unsigned)h) << 16;
    return v.f;
}
__device__ __forceinline__ bf16x8 cvt8(const float* p) {
    float4 a = *(const float4*)p;
    float4 b = *(const float4*)(p + 4);
    bf16x8 r;
    r[0] = (short)f2bf(a.x); r[1] = (short)f2bf(a.y);
    r[2] = (short)f2bf(a.z); r[3] = (short)f2bf(a.w);
    r[4] = (short)f2bf(b.x); r[5] = (short)f2bf(b.y);
    r[6] = (short)f2bf(b.z); r[7] = (short)f2bf(b.w);
    return r;
}

// ---------------------------------------------------------------------------
// Merged: z<2 -> pv{z}h[b][c][k] = bf16(sum_c' y{z}[b,k,c']*wv[c,c'] + bv[c])
//         z==2 -> kkh[b][k][d]   = bf16(sum_c' y2[b,k,c']*wk[d,c'] + bk[d])
// Grid dim3(8, 8, 3), 256 threads.
__global__ __launch_bounds__(256) void kk_pv_kernel(
    const float* __restrict__ y1, const float* __restrict__ y2,
    const float* __restrict__ wv, const float* __restrict__ bv,
    const float* __restrict__ wk, const float* __restrict__ bk,
    u16* __restrict__ pv1h, u16* __restrict__ pv2h, u16* __restrict__ kkh)
{
    const int b    = blockIdx.y;
    const int sel  = blockIdx.z;
    const int lane = threadIdx.x & 63;
    const int wid  = threadIdx.x >> 6;
    const int lr   = lane & 15;
    const int lg   = lane >> 4;

    if (sel < 2) {
        const int cb   = blockIdx.x * 64 + wid * 16;
        const float* y = sel ? y2 : y1;
        u16* pvh       = sel ? pv2h : pv1h;

        f32x4 acc[4];
        #pragma unroll
        for (int kt = 0; kt < 4; ++kt) acc[kt] = (f32x4){0.f, 0.f, 0.f, 0.f};

        for (int c0 = 0; c0 < Cn; c0 += 32) {
            const int cf = c0 + lg * 8;
            bf16x8 wfr = cvt8(wv + (size_t)(cb + lr) * Cn + cf);
            bf16x8 yfr[4];
            #pragma unroll
            for (int kt = 0; kt < 4; ++kt)
                yfr[kt] = cvt8(y + (size_t)(b * Kn + kt * 16 + lr) * Cn + cf);
            #pragma unroll
            for (int kt = 0; kt < 4; ++kt)
                acc[kt] = __builtin_amdgcn_mfma_f32_16x16x32_bf16(
                    yfr[kt], wfr, acc[kt], 0, 0, 0);
        }
        const int c = cb + lr;
        const float bb = bv[c];
        #pragma unroll
        for (int kt = 0; kt < 4; ++kt) {
            ushort4 o;
            o.x = f2bf(acc[kt][0] + bb); o.y = f2bf(acc[kt][1] + bb);
            o.z = f2bf(acc[kt][2] + bb); o.w = f2bf(acc[kt][3] + bb);
            *(ushort4*)&pvh[(((size_t)(b * Cn + c)) << 6) + kt * 16 + 4 * lg] = o;
        }
    } else {
        const int dblk = blockIdx.x * 16;
        f32x4 acc = (f32x4){0.f, 0.f, 0.f, 0.f};
        for (int c0 = 0; c0 < Cn; c0 += 32) {
            const int cf = c0 + lg * 8;
            bf16x8 wfr = cvt8(wk + (size_t)(dblk + lr) * Cn + cf);
            bf16x8 yfr = cvt8(y2 + (size_t)(b * Kn + wid * 16 + lr) * Cn + cf);
            acc = __builtin_amdgcn_mfma_f32_16x16x32_bf16(wfr, yfr, acc, 0, 0, 0);
        }
        const int d4 = dblk + 4 * lg;
        float4 bkv = *(const float4*)&bk[d4];
        ushort4 o;
        o.x = f2bf(acc[0] + bkv.x); o.y = f2bf(acc[1] + bkv.y);
        o.z = f2bf(acc[2] + bkv.z); o.w = f2bf(acc[3] + bkv.w);
        *(ushort4*)&kkh[(((size_t)(b * Kn + wid * 16 + lr)) << 7) + d4] = o;
    }
}

// ---------------------------------------------------------------------------
// Merged: x<4 -> Mth[b][k][c] = bf16(sum_d kkh[b][k][d]*wq[d,c])
//         x==4 -> e0[b,k] = sum_d bq[d]*kkh[b][k][d]
// Grid dim3(5, 8), 256 threads.
__global__ __launch_bounds__(256) void M_e0_kernel(
    const u16* __restrict__ kkh, const float* __restrict__ wq,
    const float* __restrict__ bq, u16* __restrict__ Mth,
    float* __restrict__ e0)
{
    const int b = blockIdx.y;
    const int t = threadIdx.x;

    if (blockIdx.x == 4) {
        if (t < Kn) {
            const u16* row = kkh + (((size_t)(b * Kn + t)) << 7);
            float acc = 0.f;
            #pragma unroll
            for (int d8 = 0; d8 < C4n; d8 += 8) {
                bf16x8 v = *(const bf16x8*)(row + d8);
                #pragma unroll
                for (int j = 0; j < 8; ++j)
                    acc += bq[d8 + j] * bf2f((u16)v[j]);
            }
            e0[b * Kn + t] = acc;
        }
        return;
    }

    const int cb   = blockIdx.x * 128 + (t >> 6) * 32;
    const int lane = t & 63;
    const int lr   = lane & 15;
    const int lg   = lane >> 4;

    f32x4 acc[2][4];
    #pragma unroll
    for (int ct = 0; ct < 2; ++ct)
        #pragma unroll
        for (int kt = 0; kt < 4; ++kt) acc[ct][kt] = (f32x4){0.f, 0.f, 0.f, 0.f};

    for (int d0 = 0; d0 < C4n; d0 += 32) {
        const int df = d0 + lg * 8;
        bf16x8 afr[2];
        #pragma unroll
        for (int ct = 0; ct < 2; ++ct) {
            const int c = cb + ct * 16 + lr;
            bf16x8 r;
            #pragma unroll
            for (int j = 0; j < 8; ++j)
                r[j] = (short)f2bf(wq[(size_t)(df + j) * Cn + c]);
            afr[ct] = r;
        }
        bf16x8 bfr[4];
        #pragma unroll
        for (int kt = 0; kt < 4; ++kt)
            bfr[kt] = *(const bf16x8*)&kkh[(((size_t)(b * Kn + kt * 16 + lr)) << 7) + df];
        #pragma unroll
        for (int ct = 0; ct < 2; ++ct)
            #pragma unroll
            for (int kt = 0; kt < 4; ++kt)
                acc[ct][kt] = __builtin_amdgcn_mfma_f32_16x16x32_bf16(
                    afr[ct], bfr[kt], acc[ct][kt], 0, 0, 0);
    }
    #pragma unroll
    for (int ct = 0; ct < 2; ++ct) {
        const int c4 = cb + ct * 16 + 4 * lg;
        #pragma unroll
        for (int kt = 0; kt < 4; ++kt) {
            ushort4 o;
            o.x = f2bf(acc[ct][kt][0]); o.y = f2bf(acc[ct][kt][1]);
            o.z = f2bf(acc[ct][kt][2]); o.w = f2bf(acc[ct][kt][3]);
            *(ushort4*)&Mth[(size_t)(b * Kn + kt * 16 + lr) * Cn + c4] = o;
        }
    }
}

// ---------------------------------------------------------------------------
// Fused attention+output kernel (R9 structure + phase-A depth-1 pipeline).
// Phase A: energy (operand-swapped MFMA, next-iter x2 gather prefetched) +
//          softmax -> attL (LDS, bf16, 16B-chunk XOR swizzle). One barrier.
// Phase B: per-wave independent c-stripes; att frags in regs; per-wave LDS
//          relay T for line-coalesced float4 epilogue; NT stores. No barriers.
// Grid 512 (b = id&7 XCD-affine, 64-n tile = id>>3), 256 threads.
__global__ __launch_bounds__(256) void attn_out_kernel(
    const float* __restrict__ x1, const float* __restrict__ x2,
    const u16* __restrict__ pv1h, const u16* __restrict__ pv2h,
    const u16* __restrict__ Mth, const float* __restrict__ e0,
    const float* __restrict__ scale, const float* __restrict__ scale1,
    float* __restrict__ out1, float* __restrict__ out2)
{
    __shared__ u16   attL[64 * 64];       // swizzled [n][k]
    __shared__ float T[4][16 * 68];       // per-wave epilogue relay

    const int id   = blockIdx.x;
    const int b    = id & 7;
    const int n0   = (id >> 3) * 64;
    const int t    = threadIdx.x;
    const int lane = t & 63;
    const int wid  = t >> 6;
    const int lr   = lane & 15;
    const int lg   = lane >> 4;
    const int nl   = wid * 16 + lr;       // phase-A lane's local n

    // ---------------- Phase A: energy + softmax ----------------
    f32x4 eacc[4];
    #pragma unroll
    for (int kt = 0; kt < 4; ++kt) eacc[kt] = (f32x4){0.f, 0.f, 0.f, 0.f};

    const float* xcol = x2 + (((size_t)b * Cn) << 12) + n0 + nl;  // x2[b][c][n]
    const u16*   mb   = Mth + ((size_t)b << 15) + (size_t)lr * Cn;

    // software pipeline: xs = gather for current c0, nxs = next c0
    float xs[8], nxs[8];
    #pragma unroll
    for (int j = 0; j < 8; ++j)
        xs[j] = xcol[((size_t)(lg * 8 + j)) << 12];

    for (int c0 = 0; c0 < Cn; c0 += 32) {
        const int cf = c0 + lg * 8;
        if (c0 + 32 < Cn) {   // issue next-iteration gathers before MFMAs
            #pragma unroll
            for (int j = 0; j < 8; ++j)
                nxs[j] = xcol[((size_t)(cf + 32 + j)) << 12];
        }
        bf16x8 xfr;
        #pragma unroll
        for (int j = 0; j < 8; ++j) xfr[j] = (short)f2bf(xs[j]);
        #pragma unroll
        for (int kt = 0; kt < 4; ++kt) {
            bf16x8 av = *(const bf16x8*)(mb + ((size_t)kt << 13) + cf);
            eacc[kt] = __builtin_amdgcn_mfma_f32_16x16x32_bf16(av, xfr, eacc[kt], 0, 0, 0);
        }
        #pragma unroll
        for (int j = 0; j < 8; ++j) xs[j] = nxs[j];
    }

    {
        float a[4][4];
        float mx = 0.f;   // |.| >= 0
        #pragma unroll
        for (int kt = 0; kt < 4; ++kt) {
            float4 e0v = *(const float4*)&e0[b * Kn + kt * 16 + lg * 4];
            float er[4] = {e0v.x, e0v.y, e0v.z, e0v.w};
            #pragma unroll
            for (int reg = 0; reg < 4; ++reg) {
                float v = fabsf(eacc[kt][reg] + er[reg]);
                a[kt][reg] = v;
                mx = fmaxf(mx, v);
            }
        }
        mx = fmaxf(mx, __shfl_xor(mx, 16));
        mx = fmaxf(mx, __shfl_xor(mx, 32));
        float s = 0.f;
        #pragma unroll
        for (int kt = 0; kt < 4; ++kt)
            #pragma unroll
            for (int reg = 0; reg < 4; ++reg) {
                a[kt][reg] = __expf(a[kt][reg] - mx);
                s += a[kt][reg];
            }
        s += __shfl_xor(s, 16);
        s += __shfl_xor(s, 32);
        const float inv = 1.0f / s;

        // store att row nl: k = kt*16 + 4*lg + {0..3}; 16B-chunk XOR swizzle
        #pragma unroll
        for (int kt = 0; kt < 4; ++kt) {
            ushort4 o;
            o.x = f2bf(a[kt][0] * inv); o.y = f2bf(a[kt][1] * inv);
            o.z = f2bf(a[kt][2] * inv); o.w = f2bf(a[kt][3] * inv);
            const int chunk = (kt * 2 + (lg >> 1)) ^ (nl & 7);
            *(ushort4*)&attL[nl * 64 + chunk * 8 + 4 * (lg & 1)] = o;
        }
    }
    __syncthreads();

    // att A-frags: A[row=n=nt*16+lr][k = ks*32 + lg*8 + j]
    bf16x8 af[4][2];
    #pragma unroll
    for (int nt = 0; nt < 4; ++nt)
        #pragma unroll
        for (int ks = 0; ks < 2; ++ks) {
            const int nn = nt * 16 + lr;
            const int chunk = (ks * 4 + lg) ^ (nn & 7);
            af[nt][ks] = *(const bf16x8*)&attL[nn * 64 + chunk * 8];
        }

    // ---------------- Phase B: 8 c-tiles, per-wave independent ----------------
    const float sA = scale[0], sB = scale1[0];
    float* Tw = &T[wid][0];

    for (int ct = 0; ct < 8; ++ct) {
        const int wc = ct * 64 + wid * 16;    // wave's 16-c stripe

        const u16* p1 = pv1h + (((size_t)(b * Cn + wc + lr)) << 6) + lg * 8;
        const u16* p2 = pv2h + (((size_t)(b * Cn + wc + lr)) << 6) + lg * 8;
        bf16x8 v1[2], v2[2];
        v1[0] = *(const bf16x8*)p1;  v1[1] = *(const bf16x8*)(p1 + 32);
        v2[0] = *(const bf16x8*)p2;  v2[1] = *(const bf16x8*)(p2 + 32);

        f32x4 acc1[4], acc2[4];
        #pragma unroll
        for (int nt = 0; nt < 4; ++nt) {
            f32x4 z = (f32x4){0.f, 0.f, 0.f, 0.f};
            acc1[nt] = __builtin_amdgcn_mfma_f32_16x16x32_bf16(af[nt][0], v1[0], z, 0, 0, 0);
            acc1[nt] = __builtin_amdgcn_mfma_f32_16x16x32_bf16(af[nt][1], v1[1], acc1[nt], 0, 0, 0);
            acc2[nt] = __builtin_amdgcn_mfma_f32_16x16x32_bf16(af[nt][0], v2[0], z, 0, 0, 0);
            acc2[nt] = __builtin_amdgcn_mfma_f32_16x16x32_bf16(af[nt][1], v2[1], acc2[nt], 0, 0, 0);
        }

        // ---- output 1: per-wave stage -> coalesced drain ----
        #pragma unroll
        for (int nt = 0; nt < 4; ++nt) {
            float4 v;
            v.x = acc1[nt][0]; v.y = acc1[nt][1];
            v.z = acc1[nt][2]; v.w = acc1[nt][3];
            *(float4*)&Tw[lr * 68 + nt * 16 + 4 * lg] = v;
        }
        #pragma unroll
        for (int r4 = 0; r4 < 4; ++r4) {
            const int rloc = r4 * 4 + lg;
            const size_t row = (((size_t)(b * Cn + wc + rloc)) << 12) + n0 + lr * 4;
            float4 a = *(const float4*)&Tw[rloc * 68 + lr * 4];
            float4 xv = *(const float4*)&x1[row];
            f32x4 o;
            o[0] = sA * a.x + xv.x;  o[1] = sA * a.y + xv.y;
            o[2] = sA * a.z + xv.z;  o[3] = sA * a.w + xv.w;
            __builtin_nontemporal_store(o, (f32x4*)&out1[row]);
        }

        // ---- output 2 ----
        #pragma unroll
        for (int nt = 0; nt < 4; ++nt) {
            float4 v;
            v.x = acc2[nt][0]; v.y = acc2[nt][1];
            v.z = acc2[nt][2]; v.w = acc2[nt][3];
            *(float4*)&Tw[lr * 68 + nt * 16 + 4 * lg] = v;
        }
        #pragma unroll
        for (int r4 = 0; r4 < 4; ++r4) {
            const int rloc = r4 * 4 + lg;
            const size_t row = (((size_t)(b * Cn + wc + rloc)) << 12) + n0 + lr * 4;
            float4 a = *(const float4*)&Tw[rloc * 68 + lr * 4];
            float4 xv = *(const float4*)&x2[row];
            f32x4 o;
            o[0] = sB * a.x + xv.x;  o[1] = sB * a.y + xv.y;
            o[2] = sB * a.z + xv.z;  o[3] = sB * a.w + xv.w;
            __builtin_nontemporal_store(o, (f32x4*)&out2[row]);
        }
    }
}

// ---------------------------------------------------------------------------
extern "C" void kernel_launch(void* const* d_in, const int* in_sizes, int n_in,
                              void* d_out, int out_size, void* d_ws, size_t ws_size,
                              hipStream_t stream)
{
    const float* x1     = (const float*)d_in[0];
    const float* y1     = (const float*)d_in[1];
    const float* x2     = (const float*)d_in[2];
    const float* y2     = (const float*)d_in[3];
    const float* wq     = (const float*)d_in[4];
    const float* bq     = (const float*)d_in[5];
    const float* wk     = (const float*)d_in[6];
    const float* bk     = (const float*)d_in[7];
    const float* wv     = (const float*)d_in[8];
    const float* bv     = (const float*)d_in[9];
    const float* scale  = (const float*)d_in[10];
    const float* scale1 = (const float*)d_in[11];

    float* out1 = (float*)d_out;
    float* out2 = out1 + (size_t)Bn * Cn * Nn;

    float* ws   = (float*)d_ws;
    float* e0   = ws;                       // 512 f
    u16*   kkh  = (u16*)(ws + 512);         // 65536 u16
    u16*   Mth  = kkh + 65536;              // 262144 u16
    u16*   pv1h = Mth + 262144;             // 262144 u16
    u16*   pv2h = pv1h + 262144;            // 262144 u16

    kk_pv_kernel<<<dim3(8, Bn, 3), 256, 0, stream>>>(
        y1, y2, wv, bv, wk, bk, pv1h, pv2h, kkh);
    M_e0_kernel<<<dim3(5, Bn), 256, 0, stream>>>(kkh, wq, bq, Mth, e0);
    attn_out_kernel<<<512, 256, 0, stream>>>(
        x1, x2, pv1h, pv2h, Mth, e0, scale, scale1, out1, out2);
}